// Round 5
// baseline (157.011 us; speedup 1.0000x reference)
//
#include <hip/hip_runtime.h>

// VP_lattice reverse step, B = 2^20 rows. Round-8:
//  R7 post-mortem: compiler canonicalizes to VGPR=36 regardless of source
//  order -> the 9 epilogue float2 loads are sunk to right-before-use,
//  serializing ~9 L3-hit latencies per thread with only ~4 waves/SIMD to
//  hide them. Meanwhile harness fills prove 6.6 TB/s at 8 VGPR/8% occ:
//  coalesced fire-and-forget is free; latency-bearing loads are the cost.
//  R8 structure: WAVE-LOCAL LDS staging of ALL bulk arrays.
//   - Each wave loads its 64 rows of plat/lt/pl0/zn as 9 independent
//     coalesced dwordx4/x2 (1KiB/instr), ONE vmcnt drain, ds_write to a
//     private wave slice, per-row ds_reads. ds_write consumes the loads
//     -> compiler CANNOT sink them; MLP is structural.
//   - No __syncthreads on the bulk path (wave-internal LDS ordering is
//     in-order); only one barrier per block for the schedule tables.
//   - Out assembled in the spent plat slice -> coalesced dwordx4 stores.
//     Line-requests/wave: ~390 -> ~170.
//   - LDS 38.8KB = 4x6.75KB wave slices + 11.8KB tables -> 4 blocks/CU;
//     TILES=2 amortizes table copy; grid 2048.
//  Math identical to R5-R7 (passed, absmax 0.0156).

#define NUM_STEPS 1000
#define TBL 1008
#define BLOCK 256
#define WAVES 4                 // BLOCK/64
#define TILES 2
#define RPB (BLOCK * TILES)     // 512 rows per block

// per-wave slice layout (floats)
#define W_PLAT 0
#define W_LT   576
#define W_PL0  960
#define W_ZN   1344
#define W_SZ   1728             // 6912 B per wave

// ---------------- schedule pre-kernel (runs once) ----------------
__global__ __launch_bounds__(256) void sched_kernel(
    const float* __restrict__ alpha_bars,
    const float* __restrict__ betas,
    const float* __restrict__ sigmas,
    float* __restrict__ ws)          // layout: [A[TBL] | B[TBL] | S[TBL]]
{
    int j = blockIdx.x * blockDim.x + threadIdx.x;
    if (j >= TBL) return;
    if (j <= NUM_STEPS) {
        float beta_last = betas[NUM_STEPS - 1];              // betas[-2]
        float alpha = 1.0f - fminf(betas[j], beta_last);     // clamp_min
        float coef  = 1.0f / sqrtf(alpha + 1e-8f);
        float scale = (1.0f - alpha) / sqrtf(1.0f - alpha_bars[j] + 1e-8f);
        ws[j]           = coef * (1.0f - scale);             // A
        ws[TBL + j]     = 0.5f * coef * scale;               // B
        ws[2 * TBL + j] = (j > 1) ? sigmas[j] : 0.0f;        // S (z-gated)
    } else {
        ws[j] = 0.0f; ws[TBL + j] = 0.0f; ws[2 * TBL + j] = 0.0f;
    }
}

// ---- per-row math: vec = upper-tri of sqrtm(A^T A) ----
__device__ __forceinline__ void sqrtm_vec(const float* __restrict__ pr,
                                          float vv[6])
{
    float a00 = pr[0], a01 = pr[1], a02 = pr[2];
    float a10 = pr[3], a11 = pr[4], a12 = pr[5];
    float a20 = pr[6], a21 = pr[7], a22 = pr[8];

    float m00 = a00*a00 + a10*a10 + a20*a20;
    float m01 = a00*a01 + a10*a11 + a20*a21;
    float m02 = a00*a02 + a10*a12 + a20*a22;
    float m11 = a01*a01 + a11*a11 + a21*a21;
    float m12 = a01*a02 + a11*a12 + a21*a22;
    float m22 = a02*a02 + a12*a12 + a22*a22;

    float q  = (m00 + m11 + m22) * (1.0f/3.0f);
    float b00 = m00 - q, b11 = m11 - q, b22 = m22 - q;
    float p1 = m01*m01 + m02*m02 + m12*m12;
    float p2 = b00*b00 + b11*b11 + b22*b22 + 2.0f*p1;
    float p  = sqrtf(p2 * (1.0f/6.0f));
    float detB = b00*(b11*b22 - m12*m12)
               - m01*(m01*b22 - m12*m02)
               + m02*(m01*m12 - b11*m02);
    float pinv = __fdividef(1.0f, fmaxf(p, 1e-20f));
    float r = 0.5f * detB * pinv * pinv * pinv;
    r = fminf(fmaxf(r, -1.0f), 1.0f);

    float ar = fabsf(r);
    float sq = sqrtf(1.0f - ar);
    float pl = 1.5707288f + ar * (-0.2121144f + ar * (0.0742610f - ar * 0.0187293f));
    float ac = sq * pl;
    float acr = (r >= 0.0f) ? ac : (3.14159265358979f - ac);
    float phi = acr * (1.0f/3.0f);                           // [0, pi/3]
    float mu1 = q + 2.0f*p*__cosf(phi);
    float mu3 = q + 2.0f*p*__cosf(phi + 2.0943951023931953f);
    float mu2 = 3.0f*q - mu1 - mu3;
    float l1 = sqrtf(fmaxf(mu1, 0.0f));
    float l2 = sqrtf(fmaxf(mu2, 0.0f));
    float l3 = sqrtf(fmaxf(mu3, 0.0f));

    float IU   = l1 + l2 + l3;
    float IIU  = l1*(l2 + l3) + l2*l3;
    float IIIU = l1*l2*l3;
    float denom = (l1 + l2) * (l1 + l3) * (l2 + l3);
    float dinv  = __fdividef(1.0f, fmaxf(denom, 1e-25f));
    float sd = (IU*IU - IIU) * dinv;
    float td = IU * IIIU * dinv;
    float nd = -dinv;

    float mm00 = m00*m00 + m01*m01 + m02*m02;
    float mm01 = m00*m01 + m01*m11 + m02*m12;
    float mm02 = m00*m02 + m01*m12 + m02*m22;
    float mm11 = m01*m01 + m11*m11 + m12*m12;
    float mm12 = m01*m02 + m11*m12 + m12*m22;
    float mm22 = m02*m02 + m12*m12 + m22*m22;

    vv[0] = nd*mm00 + sd*m00 + td;
    vv[1] = nd*mm01 + sd*m01;
    vv[2] = nd*mm02 + sd*m02;
    vv[3] = nd*mm11 + sd*m11 + td;
    vv[4] = nd*mm12 + sd*m12;
    vv[5] = nd*mm22 + sd*m22 + td;
}

// ---------------- main kernel ----------------
__global__ __launch_bounds__(BLOCK) void vp_lattice_kernel(
    const float* __restrict__ lt,
    const float* __restrict__ pl0,
    const float* __restrict__ plat,
    const float* __restrict__ alpha_bars,
    const float* __restrict__ betas,
    const float* __restrict__ sigmas,
    const float* __restrict__ z_noise,
    const int*   __restrict__ t,
    float* __restrict__ out,
    int n,
    const float* __restrict__ ws,
    int use_ws)
{
    __shared__ __align__(16) float sA[TBL];
    __shared__ __align__(16) float sB[TBL];
    __shared__ __align__(16) float sS[TBL];
    __shared__ __align__(16) float sW[WAVES * W_SZ];   // 27648 B wave slices

    const int tid  = threadIdx.x;
    const int lane = tid & 63;
    const int wv   = tid >> 6;
    const int rowBase = blockIdx.x * RPB;

    // ---- schedule tables into LDS (one barrier per block) ----
    if (use_ws) {
        const float4* w4 = reinterpret_cast<const float4*>(ws);
        float4* a4 = reinterpret_cast<float4*>(sA);
        float4* b4 = reinterpret_cast<float4*>(sB);
        float4* s4 = reinterpret_cast<float4*>(sS);
        for (int j = tid; j < TBL / 4; j += BLOCK) {   // 252 -> 1 iter
            a4[j] = w4[j];
            b4[j] = w4[TBL / 4 + j];
            s4[j] = w4[2 * (TBL / 4) + j];
        }
    } else {
        float beta_last = betas[NUM_STEPS - 1];
        for (int j = tid; j < TBL; j += BLOCK) {
            float A = 0.0f, Bc = 0.0f, S = 0.0f;
            if (j <= NUM_STEPS) {
                float alpha = 1.0f - fminf(betas[j], beta_last);
                float coef  = 1.0f / sqrtf(alpha + 1e-8f);
                float scale = (1.0f - alpha) / sqrtf(1.0f - alpha_bars[j] + 1e-8f);
                A  = coef * (1.0f - scale);
                Bc = 0.5f * coef * scale;
                S  = (j > 1) ? sigmas[j] : 0.0f;
            }
            sA[j] = A; sB[j] = Bc; sS[j] = S;
        }
    }
    __syncthreads();   // the ONLY barrier

    float* w = sW + wv * W_SZ;     // this wave's private slice

#pragma unroll
    for (int tile = 0; tile < TILES; ++tile) {
        const int rowW = rowBase + tile * BLOCK + wv * 64;   // wave's first row

        if (rowW + 64 <= n) {
            // ======== fast path: wave-local coalesced staging ========
            const float* gP = plat    + (size_t)rowW * 9;    // 2304 B chunk
            const float* gL = lt      + (size_t)rowW * 6;    // 1536 B chunk
            const float* gQ = pl0     + (size_t)rowW * 6;
            const float* gZ = z_noise + (size_t)rowW * 6;

            // issue ALL stage loads (9 coalesced instrs, independent)
            float4 pA = reinterpret_cast<const float4*>(gP)[lane];
            float4 pB = reinterpret_cast<const float4*>(gP)[64 + lane];
            float  pC = gP[512 + lane];
            float4 lA = reinterpret_cast<const float4*>(gL)[lane];
            float2 lB = reinterpret_cast<const float2*>(gL + 256)[lane];
            float4 qA = reinterpret_cast<const float4*>(gQ)[lane];
            float2 qB = reinterpret_cast<const float2*>(gQ + 256)[lane];
            float4 zA = reinterpret_cast<const float4*>(gZ)[lane];
            float2 zB = reinterpret_cast<const float2*>(gZ + 256)[lane];
            int ti = t[rowW + lane];                         // coalesced dword

            // ds_write to wave slice (consumes the loads -> no sinking)
            reinterpret_cast<float4*>(w + W_PLAT)[lane]      = pA;
            reinterpret_cast<float4*>(w + W_PLAT)[64 + lane] = pB;
            w[W_PLAT + 512 + lane]                           = pC;
            reinterpret_cast<float4*>(w + W_LT)[lane]        = lA;
            reinterpret_cast<float2*>(w + W_LT + 256)[lane]  = lB;
            reinterpret_cast<float4*>(w + W_PL0)[lane]       = qA;
            reinterpret_cast<float2*>(w + W_PL0 + 256)[lane] = qB;
            reinterpret_cast<float4*>(w + W_ZN)[lane]        = zA;
            reinterpret_cast<float2*>(w + W_ZN + 256)[lane]  = zB;

            // per-row reads (same wave: in-order LDS, lgkmcnt only)
            // plat row: stride 9 words (odd) = conflict-free
            float va[6];
            sqrtm_vec(w + W_PLAT + lane * 9, va);

            // table coefficients (LDS gathers)
            float A  = sA[ti];
            float Bc = sB[ti];
            float S  = sS[ti];

            // epilogue rows: stride 6 words -> b64s, 2-way (free)
            const float* lr = w + W_LT  + lane * 6;
            const float* qr = w + W_PL0 + lane * 6;
            const float* zr = w + W_ZN  + lane * 6;

            float o[6];
#pragma unroll
            for (int c = 0; c < 6; ++c) {
                float lc = lr[c];
                o[c] = A * lc + Bc * (va[c] + qr[c]) + S * zr[c];
            }

            // assemble out in the spent plat slice -> coalesced store
            float2* ow = reinterpret_cast<float2*>(w + W_PLAT);
            ow[lane * 3 + 0] = make_float2(o[0], o[1]);
            ow[lane * 3 + 1] = make_float2(o[2], o[3]);
            ow[lane * 3 + 2] = make_float2(o[4], o[5]);

            float* oG = out + (size_t)rowW * 6;
            reinterpret_cast<float4*>(oG)[lane] =
                reinterpret_cast<const float4*>(w + W_PLAT)[lane];
            reinterpret_cast<float2*>(oG + 256)[lane] =
                reinterpret_cast<const float2*>(w + W_PLAT + 256)[lane];
        } else {
            // ======== tail path (never hit at B=2^20): direct global ========
            int row = rowW + lane;
            if (row < n) {
                float ab[9];
#pragma unroll
                for (int k = 0; k < 9; ++k) ab[k] = plat[(size_t)row * 9 + k];
                float va[6];
                sqrtm_vec(ab, va);
                int ti = t[row];
                float A  = sA[ti];
                float Bc = sB[ti];
                float S  = sS[ti];
                size_t b6 = (size_t)row * 6;
#pragma unroll
                for (int c = 0; c < 6; ++c) {
                    float lc = lt[b6 + c];
                    out[b6 + c] = A * lc + Bc * (va[c] + pl0[b6 + c]) + S * z_noise[b6 + c];
                }
            }
        }
    }
}

extern "C" void kernel_launch(void* const* d_in, const int* in_sizes, int n_in,
                              void* d_out, int out_size, void* d_ws, size_t ws_size,
                              hipStream_t stream) {
    const float* lt         = (const float*)d_in[0];
    const float* pl0        = (const float*)d_in[1];
    const float* plat       = (const float*)d_in[2];
    const float* alpha_bars = (const float*)d_in[3];
    const float* betas      = (const float*)d_in[4];
    const float* sigmas     = (const float*)d_in[5];
    const float* z_noise    = (const float*)d_in[6];
    const int*   t          = (const int*)d_in[7];
    float* out = (float*)d_out;
    float* ws  = (float*)d_ws;

    int n = in_sizes[0] / 6;   // B rows
    int use_ws = (ws != nullptr && ws_size >= (size_t)(3 * TBL * sizeof(float)));

    if (use_ws) {
        sched_kernel<<<(TBL + 255) / 256, 256, 0, stream>>>(alpha_bars, betas, sigmas, ws);
    }
    int grid = (n + RPB - 1) / RPB;
    vp_lattice_kernel<<<grid, BLOCK, 0, stream>>>(
        lt, pl0, plat, alpha_bars, betas, sigmas, z_noise, t, out, n, ws, use_ws);
}

// Round 7
// 153.309 us; speedup vs baseline: 1.0241x; 1.0241x over previous
//
#include <hip/hip_runtime.h>
#include <stdint.h>

// VP_lattice reverse step, B = 2^20 rows. Round-10:
//  R9 failed correctness (absmax 8.3): the 12-byte global_load_lds variant
//  was the only HW-unverified element (learn_hip verified 4B/16B only).
//  If dwordx3's LDS lane stride is 16B-padded, lt/pl0/zn scatter into
//  neighboring regions -> O(values) error. Exactly what we saw.
//  R10: SAME structure, DMA restaged with ONLY size-16 ops (verified m97):
//   - Per-wave payload concatenated as a linear 7168B stream:
//     plat 2304 | lt 1536 | pl0 1536 | zn 1536 | t 256 = 7 x 1024B dma16.
//   - Boundary-crossing DMAs pick the source array PER-LANE (global src
//     address is per-lane free, m173); all addresses 16B-aligned since
//     wave row base is a multiple of 64.
//   - 7 fire-and-forget DMAs (7KiB in flight/wave), ONE vmcnt(0) drain
//     (+ sched_barrier, rule 18), all math from LDS. No __syncthreads.
//   - LDS 4 x 7168 = 28672B/block -> 5 blocks/CU (20 waves).
//  MLP thesis unchanged (R6-R8: VGPR-dest loads get min-pressure-scheduled
//  to ~1 outstanding/lane = 2TB/s cap). Math identical to R5-R8.

#define NUM_STEPS 1000
#define TBL 1008
#define BLOCK 256
#define WAVES 4
#define RPB 256              // rows per block, 1 per lane

// per-wave LDS stream layout (floats); byte size 7168
#define W_PLAT 0             // 576 f  (2304 B)   stream [0,2304)
#define W_LT   576           // 384 f  (1536 B)   stream [2304,3840)
#define W_PL0  960           // 384 f             stream [3840,5376)
#define W_ZN   1344          // 384 f             stream [5376,6912)
#define W_T    1728          // 64 i              stream [6912,7168)
#define W_SZF  1792          // floats per wave slice
#define W_SZB  7168          // bytes per wave slice

#define AS1 __attribute__((address_space(1)))
#define AS3 __attribute__((address_space(3)))

__device__ __forceinline__ void dma16(const void* g, void* s) {
    __builtin_amdgcn_global_load_lds((const AS1 void*)g, (AS3 void*)s, 16, 0, 0);
}

// ---------------- schedule pre-kernel (runs once) ----------------
__global__ __launch_bounds__(256) void sched_kernel(
    const float* __restrict__ alpha_bars,
    const float* __restrict__ betas,
    const float* __restrict__ sigmas,
    float4* __restrict__ ws)         // packed {A, B, S, 0} per timestep
{
    int j = blockIdx.x * blockDim.x + threadIdx.x;
    if (j >= TBL) return;
    float4 v = make_float4(0.f, 0.f, 0.f, 0.f);
    if (j <= NUM_STEPS) {
        float beta_last = betas[NUM_STEPS - 1];              // betas[-2]
        float alpha = 1.0f - fminf(betas[j], beta_last);     // clamp_min
        float coef  = 1.0f / sqrtf(alpha + 1e-8f);
        float scale = (1.0f - alpha) / sqrtf(1.0f - alpha_bars[j] + 1e-8f);
        v.x = coef * (1.0f - scale);                         // A
        v.y = 0.5f * coef * scale;                           // B
        v.z = (j > 1) ? sigmas[j] : 0.0f;                    // S (z-gated)
    }
    ws[j] = v;
}

// ---- per-row math: vec = upper-tri of sqrtm(A^T A) ----
__device__ __forceinline__ void sqrtm_vec(const float* pr, float vv[6])
{
    float a00 = pr[0], a01 = pr[1], a02 = pr[2];
    float a10 = pr[3], a11 = pr[4], a12 = pr[5];
    float a20 = pr[6], a21 = pr[7], a22 = pr[8];

    float m00 = a00*a00 + a10*a10 + a20*a20;
    float m01 = a00*a01 + a10*a11 + a20*a21;
    float m02 = a00*a02 + a10*a12 + a20*a22;
    float m11 = a01*a01 + a11*a11 + a21*a21;
    float m12 = a01*a02 + a11*a12 + a21*a22;
    float m22 = a02*a02 + a12*a12 + a22*a22;

    float q  = (m00 + m11 + m22) * (1.0f/3.0f);
    float b00 = m00 - q, b11 = m11 - q, b22 = m22 - q;
    float p1 = m01*m01 + m02*m02 + m12*m12;
    float p2 = b00*b00 + b11*b11 + b22*b22 + 2.0f*p1;
    float p  = sqrtf(p2 * (1.0f/6.0f));
    float detB = b00*(b11*b22 - m12*m12)
               - m01*(m01*b22 - m12*m02)
               + m02*(m01*m12 - b11*m02);
    float pinv = __fdividef(1.0f, fmaxf(p, 1e-20f));
    float r = 0.5f * detB * pinv * pinv * pinv;
    r = fminf(fmaxf(r, -1.0f), 1.0f);

    float ar = fabsf(r);
    float sq = sqrtf(1.0f - ar);
    float pl = 1.5707288f + ar * (-0.2121144f + ar * (0.0742610f - ar * 0.0187293f));
    float ac = sq * pl;
    float acr = (r >= 0.0f) ? ac : (3.14159265358979f - ac);
    float phi = acr * (1.0f/3.0f);                           // [0, pi/3]
    float mu1 = q + 2.0f*p*__cosf(phi);
    float mu3 = q + 2.0f*p*__cosf(phi + 2.0943951023931953f);
    float mu2 = 3.0f*q - mu1 - mu3;
    float l1 = sqrtf(fmaxf(mu1, 0.0f));
    float l2 = sqrtf(fmaxf(mu2, 0.0f));
    float l3 = sqrtf(fmaxf(mu3, 0.0f));

    float IU   = l1 + l2 + l3;
    float IIU  = l1*(l2 + l3) + l2*l3;
    float IIIU = l1*l2*l3;
    float denom = (l1 + l2) * (l1 + l3) * (l2 + l3);
    float dinv  = __fdividef(1.0f, fmaxf(denom, 1e-25f));
    float sd = (IU*IU - IIU) * dinv;
    float td = IU * IIIU * dinv;
    float nd = -dinv;

    float mm00 = m00*m00 + m01*m01 + m02*m02;
    float mm01 = m00*m01 + m01*m11 + m02*m12;
    float mm02 = m00*m02 + m01*m12 + m02*m22;
    float mm11 = m01*m01 + m11*m11 + m12*m12;
    float mm12 = m01*m02 + m11*m12 + m12*m22;
    float mm22 = m02*m02 + m12*m12 + m22*m22;

    vv[0] = nd*mm00 + sd*m00 + td;
    vv[1] = nd*mm01 + sd*m01;
    vv[2] = nd*mm02 + sd*m02;
    vv[3] = nd*mm11 + sd*m11 + td;
    vv[4] = nd*mm12 + sd*m12;
    vv[5] = nd*mm22 + sd*m22 + td;
}

// ---------------- main kernel ----------------
__global__ __launch_bounds__(BLOCK) void vp_lattice_kernel(
    const float* __restrict__ lt,
    const float* __restrict__ pl0,
    const float* __restrict__ plat,
    const float* __restrict__ alpha_bars,
    const float* __restrict__ betas,
    const float* __restrict__ sigmas,
    const float* __restrict__ z_noise,
    const int*   __restrict__ t,
    float* __restrict__ out,
    int n,
    const float4* __restrict__ coefs,
    int use_ws)
{
    __shared__ __align__(16) float sW[WAVES * W_SZF];   // 28672 B

    const int tid  = threadIdx.x;
    const int lane = tid & 63;
    const int wv   = tid >> 6;
    const int rowW = blockIdx.x * RPB + wv * 64;        // wave's first row

    float* w = sW + wv * W_SZF;                         // wave-uniform base

    if (rowW + 64 <= n) {
        // ======== fast path: 7x dma16, linear LDS stream ========
        const char* pP = (const char*)(plat    + (size_t)rowW * 9);  // 2304 B
        const char* pL = (const char*)(lt      + (size_t)rowW * 6);  // 1536 B
        const char* pQ = (const char*)(pl0     + (size_t)rowW * 6);
        const char* pZ = (const char*)(z_noise + (size_t)rowW * 6);
        const char* pT = (const char*)(t + rowW);                    // 256 B
        char* wb = (char*)w;
        const int lb = lane * 16;

        // stream s = k*1024 + lane*16; boundaries P|L|Q|Z|T at
        // 2304|3840|5376|6912|7168 — per-lane source select (16B-aligned).
        dma16(pP + lb,        wb       );                        // k0: P
        dma16(pP + 1024 + lb, wb + 1024);                        // k1: P
        { int s = 2048 + lb;                                     // k2: P|L
          dma16((s < 2304) ? pP + s : pL + (s - 2304), wb + 2048); }
        { int s = 3072 + lb;                                     // k3: L|Q
          dma16((s < 3840) ? pL + (s - 2304) : pQ + (s - 3840), wb + 3072); }
        dma16(pQ + 256 + lb,  wb + 4096);                        // k4: Q
        { int s = 5120 + lb;                                     // k5: Q|Z
          dma16((s < 5376) ? pQ + (s - 3840) : pZ + (s - 5376), wb + 5120); }
        { int s = 6144 + lb;                                     // k6: Z|T
          dma16((s < 6912) ? pZ + (s - 5376) : pT + (s - 6912), wb + 6144); }

        // single drain point (rule 18: fence + sched_barrier)
        asm volatile("s_waitcnt vmcnt(0)" ::: "memory");
        __builtin_amdgcn_sched_barrier(0);

        // timestep + coefficients (16 KB packed table, L1/L2-resident)
        int ti = reinterpret_cast<const int*>(w + W_T)[lane];
        float4 cf;
        if (use_ws) {
            cf = coefs[ti];
        } else {
            float beta_last = betas[NUM_STEPS - 1];
            float alpha = 1.0f - fminf(betas[ti], beta_last);
            float coef  = 1.0f / sqrtf(alpha + 1e-8f);
            float scale = (1.0f - alpha) / sqrtf(1.0f - alpha_bars[ti] + 1e-8f);
            cf.x = coef * (1.0f - scale);
            cf.y = 0.5f * coef * scale;
            cf.z = (ti > 1) ? sigmas[ti] : 0.0f;
        }

        // sqrtm from LDS (stride-9 words: odd -> conflict-free)
        float va[6];
        sqrtm_vec(w + W_PLAT + lane * 9, va);

        // epilogue rows from LDS (stride-6 words: 2-way, free)
        const float* lr = w + W_LT  + lane * 6;
        const float* qr = w + W_PL0 + lane * 6;
        const float* zr = w + W_ZN  + lane * 6;

        float o[6];
#pragma unroll
        for (int c = 0; c < 6; ++c) {
            float lc = lr[c];
            o[c] = cf.x * lc + cf.y * (va[c] + qr[c]) + cf.z * zr[c];
        }

        // stores: fire-and-forget float2 (write path proven cheap)
        float* oG = out + (size_t)(rowW + lane) * 6;
        reinterpret_cast<float2*>(oG)[0] = make_float2(o[0], o[1]);
        reinterpret_cast<float2*>(oG)[1] = make_float2(o[2], o[3]);
        reinterpret_cast<float2*>(oG)[2] = make_float2(o[4], o[5]);
    } else {
        // ======== tail path (not hit at B=2^20): direct per-lane ========
        int row = rowW + lane;
        if (row >= n) return;
        float ab[9];
#pragma unroll
        for (int k = 0; k < 9; ++k) ab[k] = plat[(size_t)row * 9 + k];
        float va[6];
        sqrtm_vec(ab, va);
        int ti = t[row];
        float4 cf;
        if (use_ws) {
            cf = coefs[ti];
        } else {
            float beta_last = betas[NUM_STEPS - 1];
            float alpha = 1.0f - fminf(betas[ti], beta_last);
            float coef  = 1.0f / sqrtf(alpha + 1e-8f);
            float scale = (1.0f - alpha) / sqrtf(1.0f - alpha_bars[ti] + 1e-8f);
            cf.x = coef * (1.0f - scale);
            cf.y = 0.5f * coef * scale;
            cf.z = (ti > 1) ? sigmas[ti] : 0.0f;
        }
        size_t b6 = (size_t)row * 6;
#pragma unroll
        for (int c = 0; c < 6; ++c) {
            float lc = lt[b6 + c];
            out[b6 + c] = cf.x * lc + cf.y * (va[c] + pl0[b6 + c]) + cf.z * z_noise[b6 + c];
        }
    }
}

extern "C" void kernel_launch(void* const* d_in, const int* in_sizes, int n_in,
                              void* d_out, int out_size, void* d_ws, size_t ws_size,
                              hipStream_t stream) {
    const float* lt         = (const float*)d_in[0];
    const float* pl0        = (const float*)d_in[1];
    const float* plat       = (const float*)d_in[2];
    const float* alpha_bars = (const float*)d_in[3];
    const float* betas      = (const float*)d_in[4];
    const float* sigmas     = (const float*)d_in[5];
    const float* z_noise    = (const float*)d_in[6];
    const int*   t          = (const int*)d_in[7];
    float* out = (float*)d_out;
    float4* ws = (float4*)d_ws;

    int n = in_sizes[0] / 6;   // B rows
    int use_ws = (ws != nullptr && ws_size >= (size_t)(TBL * sizeof(float4)));

    if (use_ws) {
        sched_kernel<<<(TBL + 255) / 256, 256, 0, stream>>>(alpha_bars, betas, sigmas, ws);
    }
    int grid = (n + RPB - 1) / RPB;
    vp_lattice_kernel<<<grid, BLOCK, 0, stream>>>(
        lt, pl0, plat, alpha_bars, betas, sigmas, z_noise, t, out, n, ws, use_ws);
}

// Round 8
// 151.019 us; speedup vs baseline: 1.0397x; 1.0152x over previous
//
#include <hip/hip_runtime.h>
#include <stdint.h>

// VP_lattice reverse step, B = 2^20 rows. Round-11:
//  R10 post-mortem: DMA staging (7KiB/wave in flight, 1 drain, 0 bank
//  conflicts) did NOT move the 41us/2TB/s wall -> per-wave MLP is not the
//  limiter. Wave-lifetime arithmetic: 16384 waves / 41us at ~3072 resident
//  = 7.7us lifetime vs ~1us of local work -> waves queue ~85% of life on
//  the READ path. Structure-invariant across R7/R8/R10 -> shared resource:
//  the L1 miss path. Streaming reads (zero reuse, L3 flushed by the 804MB
//  inter-iter fills) miss every line; ~32 MSHR/CU x ~900cyc congested
//  latency = ~2.3B/cyc/CU = ~2TB/s chip-wide. Matches observed exactly.
//  Writes don't use MSHRs -> fills hit 6.5TB/s at 8% occupancy.
//  R11 (single variable): NON-TEMPORAL policy on all streaming accesses.
//   - global_load_lds aux=2 (NT bit, CDNA CPol): L1 no-allocate -> misses
//     use L2's deep queues instead of L1 MSHRs.
//   - output via __builtin_nontemporal_store.
//   - coefs[ti] stays cached (16KB table, real reuse across all waves).
//  Everything else identical to R10 (passed, absmax 0.0156).

#define NUM_STEPS 1000
#define TBL 1008
#define BLOCK 256
#define WAVES 4
#define RPB 256              // rows per block, 1 per lane

// per-wave LDS stream layout (floats); byte size 7168
#define W_PLAT 0             // 576 f  (2304 B)   stream [0,2304)
#define W_LT   576           // 384 f  (1536 B)   stream [2304,3840)
#define W_PL0  960           // 384 f             stream [3840,5376)
#define W_ZN   1344          // 384 f             stream [5376,6912)
#define W_T    1728          // 64 i              stream [6912,7168)
#define W_SZF  1792          // floats per wave slice
#define W_SZB  7168          // bytes per wave slice

#define AS1 __attribute__((address_space(1)))
#define AS3 __attribute__((address_space(3)))

typedef float v2f __attribute__((ext_vector_type(2)));

// NT (non-temporal) DMA: aux=2 sets the NT CPol bit -> L1 bypass.
__device__ __forceinline__ void dma16nt(const void* g, void* s) {
    __builtin_amdgcn_global_load_lds((const AS1 void*)g, (AS3 void*)s, 16, 0, 2);
}

// ---------------- schedule pre-kernel (runs once) ----------------
__global__ __launch_bounds__(256) void sched_kernel(
    const float* __restrict__ alpha_bars,
    const float* __restrict__ betas,
    const float* __restrict__ sigmas,
    float4* __restrict__ ws)         // packed {A, B, S, 0} per timestep
{
    int j = blockIdx.x * blockDim.x + threadIdx.x;
    if (j >= TBL) return;
    float4 v = make_float4(0.f, 0.f, 0.f, 0.f);
    if (j <= NUM_STEPS) {
        float beta_last = betas[NUM_STEPS - 1];              // betas[-2]
        float alpha = 1.0f - fminf(betas[j], beta_last);     // clamp_min
        float coef  = 1.0f / sqrtf(alpha + 1e-8f);
        float scale = (1.0f - alpha) / sqrtf(1.0f - alpha_bars[j] + 1e-8f);
        v.x = coef * (1.0f - scale);                         // A
        v.y = 0.5f * coef * scale;                           // B
        v.z = (j > 1) ? sigmas[j] : 0.0f;                    // S (z-gated)
    }
    ws[j] = v;
}

// ---- per-row math: vec = upper-tri of sqrtm(A^T A) ----
__device__ __forceinline__ void sqrtm_vec(const float* pr, float vv[6])
{
    float a00 = pr[0], a01 = pr[1], a02 = pr[2];
    float a10 = pr[3], a11 = pr[4], a12 = pr[5];
    float a20 = pr[6], a21 = pr[7], a22 = pr[8];

    float m00 = a00*a00 + a10*a10 + a20*a20;
    float m01 = a00*a01 + a10*a11 + a20*a21;
    float m02 = a00*a02 + a10*a12 + a20*a22;
    float m11 = a01*a01 + a11*a11 + a21*a21;
    float m12 = a01*a02 + a11*a12 + a21*a22;
    float m22 = a02*a02 + a12*a12 + a22*a22;

    float q  = (m00 + m11 + m22) * (1.0f/3.0f);
    float b00 = m00 - q, b11 = m11 - q, b22 = m22 - q;
    float p1 = m01*m01 + m02*m02 + m12*m12;
    float p2 = b00*b00 + b11*b11 + b22*b22 + 2.0f*p1;
    float p  = sqrtf(p2 * (1.0f/6.0f));
    float detB = b00*(b11*b22 - m12*m12)
               - m01*(m01*b22 - m12*m02)
               + m02*(m01*m12 - b11*m02);
    float pinv = __fdividef(1.0f, fmaxf(p, 1e-20f));
    float r = 0.5f * detB * pinv * pinv * pinv;
    r = fminf(fmaxf(r, -1.0f), 1.0f);

    float ar = fabsf(r);
    float sq = sqrtf(1.0f - ar);
    float pl = 1.5707288f + ar * (-0.2121144f + ar * (0.0742610f - ar * 0.0187293f));
    float ac = sq * pl;
    float acr = (r >= 0.0f) ? ac : (3.14159265358979f - ac);
    float phi = acr * (1.0f/3.0f);                           // [0, pi/3]
    float mu1 = q + 2.0f*p*__cosf(phi);
    float mu3 = q + 2.0f*p*__cosf(phi + 2.0943951023931953f);
    float mu2 = 3.0f*q - mu1 - mu3;
    float l1 = sqrtf(fmaxf(mu1, 0.0f));
    float l2 = sqrtf(fmaxf(mu2, 0.0f));
    float l3 = sqrtf(fmaxf(mu3, 0.0f));

    float IU   = l1 + l2 + l3;
    float IIU  = l1*(l2 + l3) + l2*l3;
    float IIIU = l1*l2*l3;
    float denom = (l1 + l2) * (l1 + l3) * (l2 + l3);
    float dinv  = __fdividef(1.0f, fmaxf(denom, 1e-25f));
    float sd = (IU*IU - IIU) * dinv;
    float td = IU * IIIU * dinv;
    float nd = -dinv;

    float mm00 = m00*m00 + m01*m01 + m02*m02;
    float mm01 = m00*m01 + m01*m11 + m02*m12;
    float mm02 = m00*m02 + m01*m12 + m02*m22;
    float mm11 = m01*m01 + m11*m11 + m12*m12;
    float mm12 = m01*m02 + m11*m12 + m12*m22;
    float mm22 = m02*m02 + m12*m12 + m22*m22;

    vv[0] = nd*mm00 + sd*m00 + td;
    vv[1] = nd*mm01 + sd*m01;
    vv[2] = nd*mm02 + sd*m02;
    vv[3] = nd*mm11 + sd*m11 + td;
    vv[4] = nd*mm12 + sd*m12;
    vv[5] = nd*mm22 + sd*m22 + td;
}

// ---------------- main kernel ----------------
__global__ __launch_bounds__(BLOCK) void vp_lattice_kernel(
    const float* __restrict__ lt,
    const float* __restrict__ pl0,
    const float* __restrict__ plat,
    const float* __restrict__ alpha_bars,
    const float* __restrict__ betas,
    const float* __restrict__ sigmas,
    const float* __restrict__ z_noise,
    const int*   __restrict__ t,
    float* __restrict__ out,
    int n,
    const float4* __restrict__ coefs,
    int use_ws)
{
    __shared__ __align__(16) float sW[WAVES * W_SZF];   // 28672 B

    const int tid  = threadIdx.x;
    const int lane = tid & 63;
    const int wv   = tid >> 6;
    const int rowW = blockIdx.x * RPB + wv * 64;        // wave's first row

    float* w = sW + wv * W_SZF;                         // wave-uniform base

    if (rowW + 64 <= n) {
        // ======== fast path: 7x NT dma16, linear LDS stream ========
        const char* pP = (const char*)(plat    + (size_t)rowW * 9);  // 2304 B
        const char* pL = (const char*)(lt      + (size_t)rowW * 6);  // 1536 B
        const char* pQ = (const char*)(pl0     + (size_t)rowW * 6);
        const char* pZ = (const char*)(z_noise + (size_t)rowW * 6);
        const char* pT = (const char*)(t + rowW);                    // 256 B
        char* wb = (char*)w;
        const int lb = lane * 16;

        // stream s = k*1024 + lane*16; boundaries P|L|Q|Z|T at
        // 2304|3840|5376|6912|7168 — per-lane source select (16B-aligned).
        dma16nt(pP + lb,        wb       );                      // k0: P
        dma16nt(pP + 1024 + lb, wb + 1024);                      // k1: P
        { int s = 2048 + lb;                                     // k2: P|L
          dma16nt((s < 2304) ? pP + s : pL + (s - 2304), wb + 2048); }
        { int s = 3072 + lb;                                     // k3: L|Q
          dma16nt((s < 3840) ? pL + (s - 2304) : pQ + (s - 3840), wb + 3072); }
        dma16nt(pQ + 256 + lb,  wb + 4096);                      // k4: Q
        { int s = 5120 + lb;                                     // k5: Q|Z
          dma16nt((s < 5376) ? pQ + (s - 3840) : pZ + (s - 5376), wb + 5120); }
        { int s = 6144 + lb;                                     // k6: Z|T
          dma16nt((s < 6912) ? pZ + (s - 5376) : pT + (s - 6912), wb + 6144); }

        // single drain point (rule 18: fence + sched_barrier)
        asm volatile("s_waitcnt vmcnt(0)" ::: "memory");
        __builtin_amdgcn_sched_barrier(0);

        // timestep + coefficients (16 KB packed table: CACHED, has reuse)
        int ti = reinterpret_cast<const int*>(w + W_T)[lane];
        float4 cf;
        if (use_ws) {
            cf = coefs[ti];
        } else {
            float beta_last = betas[NUM_STEPS - 1];
            float alpha = 1.0f - fminf(betas[ti], beta_last);
            float coef  = 1.0f / sqrtf(alpha + 1e-8f);
            float scale = (1.0f - alpha) / sqrtf(1.0f - alpha_bars[ti] + 1e-8f);
            cf.x = coef * (1.0f - scale);
            cf.y = 0.5f * coef * scale;
            cf.z = (ti > 1) ? sigmas[ti] : 0.0f;
        }

        // sqrtm from LDS (stride-9 words: odd -> conflict-free)
        float va[6];
        sqrtm_vec(w + W_PLAT + lane * 9, va);

        // epilogue rows from LDS (stride-6 words: 2-way, free)
        const float* lr = w + W_LT  + lane * 6;
        const float* qr = w + W_PL0 + lane * 6;
        const float* zr = w + W_ZN  + lane * 6;

        float o[6];
#pragma unroll
        for (int c = 0; c < 6; ++c) {
            float lc = lr[c];
            o[c] = cf.x * lc + cf.y * (va[c] + qr[c]) + cf.z * zr[c];
        }

        // non-temporal stores (streaming output, no reuse)
        v2f* oG = (v2f*)(out + (size_t)(rowW + lane) * 6);
        v2f s0; s0.x = o[0]; s0.y = o[1];
        v2f s1; s1.x = o[2]; s1.y = o[3];
        v2f s2; s2.x = o[4]; s2.y = o[5];
        __builtin_nontemporal_store(s0, oG + 0);
        __builtin_nontemporal_store(s1, oG + 1);
        __builtin_nontemporal_store(s2, oG + 2);
    } else {
        // ======== tail path (not hit at B=2^20): direct per-lane ========
        int row = rowW + lane;
        if (row >= n) return;
        float ab[9];
#pragma unroll
        for (int k = 0; k < 9; ++k) ab[k] = plat[(size_t)row * 9 + k];
        float va[6];
        sqrtm_vec(ab, va);
        int ti = t[row];
        float4 cf;
        if (use_ws) {
            cf = coefs[ti];
        } else {
            float beta_last = betas[NUM_STEPS - 1];
            float alpha = 1.0f - fminf(betas[ti], beta_last);
            float coef  = 1.0f / sqrtf(alpha + 1e-8f);
            float scale = (1.0f - alpha) / sqrtf(1.0f - alpha_bars[ti] + 1e-8f);
            cf.x = coef * (1.0f - scale);
            cf.y = 0.5f * coef * scale;
            cf.z = (ti > 1) ? sigmas[ti] : 0.0f;
        }
        size_t b6 = (size_t)row * 6;
#pragma unroll
        for (int c = 0; c < 6; ++c) {
            float lc = lt[b6 + c];
            out[b6 + c] = cf.x * lc + cf.y * (va[c] + pl0[b6 + c]) + cf.z * z_noise[b6 + c];
        }
    }
}

extern "C" void kernel_launch(void* const* d_in, const int* in_sizes, int n_in,
                              void* d_out, int out_size, void* d_ws, size_t ws_size,
                              hipStream_t stream) {
    const float* lt         = (const float*)d_in[0];
    const float* pl0        = (const float*)d_in[1];
    const float* plat       = (const float*)d_in[2];
    const float* alpha_bars = (const float*)d_in[3];
    const float* betas      = (const float*)d_in[4];
    const float* sigmas     = (const float*)d_in[5];
    const float* z_noise    = (const float*)d_in[6];
    const int*   t          = (const int*)d_in[7];
    float* out = (float*)d_out;
    float4* ws = (float4*)d_ws;

    int n = in_sizes[0] / 6;   // B rows
    int use_ws = (ws != nullptr && ws_size >= (size_t)(TBL * sizeof(float4)));

    if (use_ws) {
        sched_kernel<<<(TBL + 255) / 256, 256, 0, stream>>>(alpha_bars, betas, sigmas, ws);
    }
    int grid = (n + RPB - 1) / RPB;
    vp_lattice_kernel<<<grid, BLOCK, 0, stream>>>(
        lt, pl0, plat, alpha_bars, betas, sigmas, z_noise, t, out, n, ws, use_ws);
}